// Round 3
// baseline (123.223 us; speedup 1.0000x reference)
//
#include <hip/hip_runtime.h>

// Euler characteristic curve (ECC) of V-construction cubical complex.
// x: [64,3,224,224] fp32 in [0,1). Out: [64,96] fp32 = per-(b,c) ECC over
// tseq = linspace(0,1,32); out[img*32+t], img = b*3+c.
//
// Cell->bin: bin(f) = ceil(31*f); monotonic so bin(max) = max(bin).
// Net-update formulation (one histogram slot per pixel per family):
//   pair1 (vertex/h-edge) at pixel k, d_k = [B_{k+1}>B_k]:  @B_k: d_k - d_{k-1}
//   pair2 (v-edge/square) along M_k = max(B_k,C_k), e_k = [M_{k+1}>M_k]:
//                                                           @M_k: e_{k-1} - e_k
// Sentinels: RIGHT neighbor of col 223 -> bin 64 (always-true). LEFT neighbor
// of col 0 -> bin 63 (always >=). Bottom row (r==H-1) skips pair2.
//
// R11 — DIAGNOSTIC ROUND (measurement, not optimization). R9 (atomics) and
// R10 (plain RMW) both land at ~75-77 us total; the LDS-substrate theory is
// falsified, and the ECC kernel has NEVER appeared in rocprof top-5 (the
// harness's 43-us 256MiB re-poison fill crowds it out), so every theory so
// far was fit to an inferred time with zero counters. This round repeats the
// pixel-processing section PASSES=8 times, accumulating into the SAME live
// per-wave histograms (no DCE possible — all passes feed the final output;
// rule 17). An opaque zero ('+v' inline asm) is added to the row base each
// pass so the compiler must re-issue the global loads. Bias per packed
// 16-bit half raised 64 -> 1024 so 8x accumulation (|net| <= 56/pass) never
// borrows/carries across the half boundary. Reduction subtracts 256*1024
// and >>3. Output bit-identical to R10 (absmax=0 expected).
//
// Read-out: dur_us = 76.9 + 7*T (T = true per-pass kernel cost), and for
// T > 5.5 us the kernel enters top-5 with VALUBusy / OccupancyPercent /
// FETCH_SIZE / SQ_LDS_BANK_CONFLICT — naming the real bottleneck for R12.

#define H 224
#define W 224
#define STEPS 32
#define NWORDS 17           // 33 bins packed 2/word; bin 32 (f==1.0) safe slot
#define NCOL 64
#define SLAB (NWORDS * NCOL)   // 1088 ints per wave slab
#define BANDS 8
#define BAND_ROWS 28        // rows per block
#define SUB_ROWS 7          // rows per wave (4 waves per block)
#define NTHR 256
#define PASSES 8
#define BIAS 1024
#define BIASW 0x04000400    // bias 1024 in each 16-bit half

__device__ __forceinline__ int bin_of(float f) {
    // ceil(31*f) for f in [0,1): fma then trunc. 0.99999994f = 1-2^-24.
    return (int)fmaf(f, 31.0f, 0.99999994f);
}

// Packed-halfword histogram add: word (bin>>1), half (bin&1), value v in
// {-1,0,1}. Low half: += v (bias prevents borrow into high half). High half:
// += v<<16 (wraps mod 2^32, low half untouched). Plain LDS RMW.
__device__ __forceinline__ void hist_add(int* __restrict__ lhw, int bin, int v) {
    lhw[(bin >> 1) << 6] += (v << ((bin & 1) << 4));
}

struct BinState {
    int B0, B1, B2, B3, Bn, Bp;
};

// pair1: net vertex/h-edge updates at the 4 own pixels.
__device__ __forceinline__ void pair1_update(int* __restrict__ lhw,
                                             const BinState& S)
{
    int dm = (S.B0 > S.Bp) ? 1 : 0;
    int d0 = (S.B1 > S.B0) ? 1 : 0;
    int d1 = (S.B2 > S.B1) ? 1 : 0;
    int d2 = (S.B3 > S.B2) ? 1 : 0;
    int d3 = (S.Bn > S.B3) ? 1 : 0;
    hist_add(lhw, S.B0, d0 - dm);
    hist_add(lhw, S.B1, d1 - d0);
    hist_add(lhw, S.B2, d2 - d1);
    hist_add(lhw, S.B3, d3 - d2);
}

// pair2: net v-edge/square updates along M = max(B, C); rolls S <- C bins.
__device__ __forceinline__ void pair2_update_roll(int* __restrict__ lhw,
                                                  BinState& S, float4 G,
                                                  bool lastc, bool firstc)
{
    int C0 = bin_of(G.x), C1 = bin_of(G.y), C2 = bin_of(G.z), C3 = bin_of(G.w);
    int t;
    t = __shfl_down(C0, 1); int Cn = lastc  ? 64 : t;
    t = __shfl_up  (C3, 1); int Cp = firstc ? 63 : t;

    int M0 = max(S.B0, C0), M1 = max(S.B1, C1),
        M2 = max(S.B2, C2), M3 = max(S.B3, C3);
    int Mn = max(S.Bn, Cn), Mp = max(S.Bp, Cp);
    int em = (M0 > Mp) ? 1 : 0;
    int e0 = (M1 > M0) ? 1 : 0;
    int e1 = (M2 > M1) ? 1 : 0;
    int e2 = (M3 > M2) ? 1 : 0;
    int e3 = (Mn > M3) ? 1 : 0;
    hist_add(lhw, M0, em - e0);
    hist_add(lhw, M1, e0 - e1);
    hist_add(lhw, M2, e1 - e2);
    hist_add(lhw, M3, e2 - e3);

    S.B0 = C0; S.B1 = C1; S.B2 = C2; S.B3 = C3; S.Bn = Cn; S.Bp = Cp;
}

__global__ __launch_bounds__(NTHR, 6) void ecc_fused_kernel(
        const float* __restrict__ x, float* __restrict__ out)
{
    // Per-wave private packed slabs: no atomics in the hot loop.
    // RMW addr word = s*1088 + (bin>>1)*64 + c: bank = c%32 -> 2-way (free).
    __shared__ int lh[4 * SLAB];     // 17408 B
    __shared__ int bins[STEPS];

    const int tid = threadIdx.x;
    for (int i = tid; i < 4 * SLAB; i += NTHR) lh[i] = BIASW;
    __syncthreads();

    const int band = blockIdx.x & (BANDS - 1);
    const int img  = blockIdx.x / BANDS;          // 0..191
    const float* __restrict__ p = x + (size_t)img * (H * W);

    const int c = tid & 63;      // column group: cols 4c..4c+3 (active c<56); c==lane
    const int s = tid >> 6;      // sub-band id == wave id (rows uniform per wave)

    if (c < 56) {
        const bool lastc  = (c == 55);
        const bool firstc = (c == 0);
        const int  r0 = band * BAND_ROWS + s * SUB_ROWS;
        int* __restrict__ lhw = lh + s * SLAB + c;   // private wave slab + own column

        #pragma unroll 1
        for (int pass = 0; pass < PASSES; ++pass) {
            // Opaque zero: compiler must re-issue global loads each pass
            // (prevents register-caching of the 7-row unrolled loads).
            int zoff = 0;
            asm volatile("" : "+v"(zoff));

            const float* __restrict__ row = p + r0 * W + (c << 2) + zoff;
            float4 F = *(const float4*)row;
            BinState S;
            S.B0 = bin_of(F.x); S.B1 = bin_of(F.y);
            S.B2 = bin_of(F.z); S.B3 = bin_of(F.w);
            int t;
            t = __shfl_down(S.B0, 1); S.Bn = lastc  ? 64 : t;  // right: always-greater
            t = __shfl_up  (S.B3, 1); S.Bp = firstc ? 63 : t;  // left: never-smaller

            if (r0 != H - SUB_ROWS) {
                // Interior wave: branch-free unrolled body, loads pipeline ahead (R9).
                #pragma unroll
                for (int k = 0; k < SUB_ROWS; ++k) {
                    pair1_update(lhw, S);
                    float4 G = *(const float4*)(row + W);
                    pair2_update_roll(lhw, S, G, lastc, firstc);
                    row += W;
                }
            } else {
                // The single boundary wave (band 7, sub-band 3): 6 full rows,
                // then pair1-only on the bottom row (r == H-1).
                #pragma unroll
                for (int k = 0; k < SUB_ROWS - 1; ++k) {
                    pair1_update(lhw, S);
                    float4 G = *(const float4*)(row + W);
                    pair2_update_roll(lhw, S, G, lastc, firstc);
                    row += W;
                }
                pair1_update(lhw, S);
            }
        }
    }
    __syncthreads();

    // Reduce 4 slabs x 64 columns -> 32 bin sums. Thread (b,g): b = bin,
    // g = 8-lane group; extracts half (b&1) of word (b>>1) across g's 8
    // columns in each slab. 256 biased halves per bin, each holding
    // BIAS + 8*true -> subtract 256*BIAS, then >>3 (exact: multiple of 8).
    const int b = tid >> 3;              // 0..31
    const int g = tid & 7;
    const int hsh = (b & 1) << 4;
    int sum = 0;
    #pragma unroll
    for (int s2 = 0; s2 < 4; ++s2) {
        const int4* rp = (const int4*)(lh + s2 * SLAB + ((b >> 1) << 6) + (g << 3));
        int4 u0 = rp[0], u1 = rp[1];
        sum += ((u0.x >> hsh) & 0xFFFF) + ((u0.y >> hsh) & 0xFFFF)
             + ((u0.z >> hsh) & 0xFFFF) + ((u0.w >> hsh) & 0xFFFF)
             + ((u1.x >> hsh) & 0xFFFF) + ((u1.y >> hsh) & 0xFFFF)
             + ((u1.z >> hsh) & 0xFFFF) + ((u1.w >> hsh) & 0xFFFF);
    }
    sum += __shfl_xor(sum, 1);
    sum += __shfl_xor(sum, 2);
    sum += __shfl_xor(sum, 4);
    if (g == 0) bins[b] = (sum - 256 * BIAS) >> 3;   // strip bias, /PASSES
    __syncthreads();

    // Wave 0, lanes 0..31: inclusive prefix over bins, then one float
    // atomicAdd per bin into d_out (8 band blocks accumulate per image).
    if (tid < STEPS) {
        int v = bins[tid];
        #pragma unroll
        for (int off = 1; off < STEPS; off <<= 1) {
            int u = __shfl_up(v, off);
            if (tid >= off) v += u;
        }
        atomicAdd(&out[img * STEPS + tid], (float)v);
    }
}

extern "C" void kernel_launch(void* const* d_in, const int* in_sizes, int n_in,
                              void* d_out, int out_size, void* d_ws, size_t ws_size,
                              hipStream_t stream) {
    const float* x = (const float*)d_in[0];
    float* out = (float*)d_out;

    const int nimg = in_sizes[0] / (H * W);      // 192

    dim3 grid(nimg * BANDS);
    ecc_fused_kernel<<<grid, NTHR, 0, stream>>>(x, out);
}

// Round 4
// 100.080 us; speedup vs baseline: 1.2312x; 1.2312x over previous
//
#include <hip/hip_runtime.h>

// Euler characteristic curve (ECC) of V-construction cubical complex.
// x: [64,3,224,224] fp32 in [0,1). Out: [64,96] fp32 = per-(b,c) ECC over
// tseq = linspace(0,1,32); out[img*32+t], img = b*3+c.
//
// Cell->bin: bin(f) = ceil(31*f); monotonic so bin(max) = max(bin).
// Net-update formulation (one atomic slot per pixel per family):
//   pair1 (vertex/h-edge) at pixel k, d_k = [B_{k+1}>B_k]:  @B_k: d_k - d_{k-1}
//   pair2 (v-edge/square) along M_k = max(B_k,C_k), e_k = [M_{k+1}>M_k]:
//                                                           @M_k: e_{k-1} - e_k
// Sentinels: RIGHT neighbor of col 223 -> bin 64 (always-true). LEFT neighbor
// of col 0 -> bin 63 (always >=). Bottom row (r==H-1) skips pair2.
// Math verified absmax=0 (R7..R11).
//
// R11 DIAGNOSTIC RESULT (8-pass repeat): dur = fill(43) + kernel + ~16 us
// overhead. Warm compute pass = 6.6 us (VALUBusy 75%, issue-bound);
// single-pass kernel ~17.6 us => ~10-11 us is EXPOSED MEMORY TIME
// (42 MB fetch = 6.7 us at BW roofline, paid at ~40% peak with poor
// overlap). VGPR_Count=28 proves the compiler kept only 1-2 row loads in
// flight -> each wave serially exposes HBM/L3 latency on its 7-row chain.
// LDS substrate is NOT the bottleneck (R9 atomics == R10 RMW).
//
// R12: (a) revert to R9's unpacked 33-bin LDS hist + ds-atomicAdd (leanest
// per-update: 1 addr op + 1 ds_add; R10's packing added shift fat for zero
// gain); (b) BULK REGISTER PREFETCH: issue all 8 row loads back-to-back
// into named float4 registers before any compute (T14 issue-early/
// use-late), overlap LDS init + syncthreads with the in-flight loads, run
// the whole compute loop from registers. Converts the serial per-row
// latency chain into one BW-bound drain overlapped with compute.
// Predicted: kernel 17.6 -> ~10-12 us, dur_us 76.9 -> ~69-71.

#define H 224
#define W 224
#define STEPS 32
#define NBINS 33            // bin 32 (f==1.0 edge case) kept memory-safe, discarded
#define NCOL 64
#define BANDS 8
#define BAND_ROWS 28        // rows per block
#define SUB_ROWS 7          // rows per wave (4 waves per block)
#define NTHR 256

__device__ __forceinline__ int bin_of(float f) {
    // ceil(31*f) for f in [0,1): fma then trunc. 0.99999994f = 1-2^-24.
    return (int)fmaf(f, 31.0f, 0.99999994f);
}

struct BinState {
    int B0, B1, B2, B3, Bn, Bp;
};

// pair1: net vertex/h-edge updates at the 4 own pixels (unpredicated ds_add).
__device__ __forceinline__ void pair1_update(int* __restrict__ lhc,
                                             const BinState& S)
{
    int dm = (S.B0 > S.Bp) ? 1 : 0;
    int d0 = (S.B1 > S.B0) ? 1 : 0;
    int d1 = (S.B2 > S.B1) ? 1 : 0;
    int d2 = (S.B3 > S.B2) ? 1 : 0;
    int d3 = (S.Bn > S.B3) ? 1 : 0;
    atomicAdd(&lhc[S.B0 << 6], d0 - dm);
    atomicAdd(&lhc[S.B1 << 6], d1 - d0);
    atomicAdd(&lhc[S.B2 << 6], d2 - d1);
    atomicAdd(&lhc[S.B3 << 6], d3 - d2);
}

// pair2: net v-edge/square updates along M = max(B, C); rolls S <- C bins.
__device__ __forceinline__ void pair2_update_roll(int* __restrict__ lhc,
                                                  BinState& S, float4 G,
                                                  bool lastc, bool firstc)
{
    int C0 = bin_of(G.x), C1 = bin_of(G.y), C2 = bin_of(G.z), C3 = bin_of(G.w);
    int t;
    t = __shfl_down(C0, 1); int Cn = lastc  ? 64 : t;
    t = __shfl_up  (C3, 1); int Cp = firstc ? 63 : t;

    int M0 = max(S.B0, C0), M1 = max(S.B1, C1),
        M2 = max(S.B2, C2), M3 = max(S.B3, C3);
    int Mn = max(S.Bn, Cn), Mp = max(S.Bp, Cp);
    int em = (M0 > Mp) ? 1 : 0;
    int e0 = (M1 > M0) ? 1 : 0;
    int e1 = (M2 > M1) ? 1 : 0;
    int e2 = (M3 > M2) ? 1 : 0;
    int e3 = (Mn > M3) ? 1 : 0;
    atomicAdd(&lhc[M0 << 6], em - e0);
    atomicAdd(&lhc[M1 << 6], e0 - e1);
    atomicAdd(&lhc[M2 << 6], e1 - e2);
    atomicAdd(&lhc[M3 << 6], e2 - e3);

    S.B0 = C0; S.B1 = C1; S.B2 = C2; S.B3 = C3; S.Bn = Cn; S.Bp = Cp;
}

__global__ __launch_bounds__(NTHR, 6) void ecc_fused_kernel(
        const float* __restrict__ x, float* __restrict__ out)
{
    // Shared across the block's 4 waves. Update addr = (bin*64 + c)*4:
    // bank = c%32 -> 2-way wave aliasing (free, m136).
    __shared__ int lh[NBINS * NCOL];     // 8448 B
    __shared__ int bins[STEPS];

    const int tid  = threadIdx.x;
    const int band = blockIdx.x & (BANDS - 1);
    const int img  = blockIdx.x / BANDS;          // 0..191
    const float* __restrict__ p = x + (size_t)img * (H * W);

    const int c = tid & 63;      // column group: cols 4c..4c+3 (active c<56); c==lane
    const int s = tid >> 6;      // sub-band id == wave id (rows uniform per wave)
    const int r0 = band * BAND_ROWS + s * SUB_ROWS;

    // --- Bulk prefetch: 8 back-to-back global_load_dwordx4 per lane. ---
    // All of this wave's data is demanded up front -> the memory system
    // sees the full 42 MB working set immediately and streams at BW;
    // latency is hidden behind LDS init + syncthreads + earlier rows'
    // compute instead of being exposed serially per row (R9..R11 had
    // VGPR_Count=28 -> at most 1-2 loads in flight).
    float4 F0, F1, F2, F3, F4, F5, F6, F7;
    if (c < 56) {
        const float* __restrict__ base = p + (c << 2);
        F0 = *(const float4*)(base + (size_t)(r0    ) * W);
        F1 = *(const float4*)(base + (size_t)(r0 + 1) * W);
        F2 = *(const float4*)(base + (size_t)(r0 + 2) * W);
        F3 = *(const float4*)(base + (size_t)(r0 + 3) * W);
        F4 = *(const float4*)(base + (size_t)(r0 + 4) * W);
        F5 = *(const float4*)(base + (size_t)(r0 + 5) * W);
        F6 = *(const float4*)(base + (size_t)(r0 + 6) * W);
        const int r7 = (r0 + 7 < H) ? (r0 + 7) : (H - 1);  // boundary wave clamp
        F7 = *(const float4*)(base + (size_t)r7 * W);      // unused value there
    }

    // LDS init + barrier overlap the in-flight loads (DS pipe vs VMEM).
    for (int i = tid; i < NBINS * NCOL; i += NTHR) lh[i] = 0;
    __syncthreads();

    if (c < 56) {
        const bool lastc  = (c == 55);
        const bool firstc = (c == 0);
        int* __restrict__ lhc = lh + c;

        BinState S;
        S.B0 = bin_of(F0.x); S.B1 = bin_of(F0.y);
        S.B2 = bin_of(F0.z); S.B3 = bin_of(F0.w);
        int t;
        t = __shfl_down(S.B0, 1); S.Bn = lastc  ? 64 : t;  // right: always-greater
        t = __shfl_up  (S.B3, 1); S.Bp = firstc ? 63 : t;  // left: never-smaller

        if (r0 != H - SUB_ROWS) {
            // Interior wave: rows r0..r0+6 all have a row below.
            pair1_update(lhc, S); pair2_update_roll(lhc, S, F1, lastc, firstc);
            pair1_update(lhc, S); pair2_update_roll(lhc, S, F2, lastc, firstc);
            pair1_update(lhc, S); pair2_update_roll(lhc, S, F3, lastc, firstc);
            pair1_update(lhc, S); pair2_update_roll(lhc, S, F4, lastc, firstc);
            pair1_update(lhc, S); pair2_update_roll(lhc, S, F5, lastc, firstc);
            pair1_update(lhc, S); pair2_update_roll(lhc, S, F6, lastc, firstc);
            pair1_update(lhc, S); pair2_update_roll(lhc, S, F7, lastc, firstc);
        } else {
            // The single boundary wave (band 7, sub-band 3): 6 full rows,
            // then pair1-only on the bottom row (r == H-1).
            pair1_update(lhc, S); pair2_update_roll(lhc, S, F1, lastc, firstc);
            pair1_update(lhc, S); pair2_update_roll(lhc, S, F2, lastc, firstc);
            pair1_update(lhc, S); pair2_update_roll(lhc, S, F3, lastc, firstc);
            pair1_update(lhc, S); pair2_update_roll(lhc, S, F4, lastc, firstc);
            pair1_update(lhc, S); pair2_update_roll(lhc, S, F5, lastc, firstc);
            pair1_update(lhc, S); pair2_update_roll(lhc, S, F6, lastc, firstc);
            pair1_update(lhc, S);
        }
    }
    __syncthreads();

    // Reduce 64 columns -> 32 bin sums (bin 32, if ever hit, discarded).
    // tid = b*8+g: 8-lane groups are 8-aligned, shfl_xor 1/2/4 stays in-group.
    const int b = tid >> 3;              // 0..31
    const int g = tid & 7;
    const int4* rowp = (const int4*)(lh + (b << 6) + (g << 3));
    int4 u0 = rowp[0], u1 = rowp[1];
    int sum = u0.x + u0.y + u0.z + u0.w + u1.x + u1.y + u1.z + u1.w;
    sum += __shfl_xor(sum, 1);
    sum += __shfl_xor(sum, 2);
    sum += __shfl_xor(sum, 4);
    if (g == 0) bins[b] = sum;
    __syncthreads();

    // Wave 0, lanes 0..31: inclusive prefix over bins, then one float
    // atomicAdd per bin into d_out (8 band blocks accumulate per image).
    if (tid < STEPS) {
        int v = bins[tid];
        #pragma unroll
        for (int off = 1; off < STEPS; off <<= 1) {
            int u = __shfl_up(v, off);
            if (tid >= off) v += u;
        }
        atomicAdd(&out[img * STEPS + tid], (float)v);
    }
}

extern "C" void kernel_launch(void* const* d_in, const int* in_sizes, int n_in,
                              void* d_out, int out_size, void* d_ws, size_t ws_size,
                              hipStream_t stream) {
    const float* x = (const float*)d_in[0];
    float* out = (float*)d_out;

    const int nimg = in_sizes[0] / (H * W);      // 192

    dim3 grid(nimg * BANDS);
    ecc_fused_kernel<<<grid, NTHR, 0, stream>>>(x, out);
}

// Round 5
// 76.601 us; speedup vs baseline: 1.6086x; 1.3065x over previous
//
#include <hip/hip_runtime.h>

// Euler characteristic curve (ECC) of V-construction cubical complex.
// x: [64,3,224,224] fp32 in [0,1). Out: [64,96] fp32 = per-(b,c) ECC over
// tseq = linspace(0,1,32); out[img*32+t], img = b*3+c.
//
// Cell->bin: bin(f) = ceil(31*f); monotonic so bin(max) = max(bin).
// Net-update formulation (one atomic slot per pixel per family):
//   pair1 (vertex/h-edge) at pixel k, d_k = [B_{k+1}>B_k]:  @B_k: d_k - d_{k-1}
//   pair2 (v-edge/square) along M_k = max(B_k,C_k), e_k = [M_{k+1}>M_k]:
//                                                           @M_k: e_{k-1} - e_k
// Sentinels: RIGHT neighbor of col 223 -> bin 64 (always-true). LEFT neighbor
// of col 0 -> bin 63 (always >=). Bottom row (r==H-1) skips pair2.
// Math verified absmax=0 (R7..R12).
//
// History: R11 diagnostic: warm compute 6.6us (VALUBusy 75%), single-pass
// kernel 17.6us => ~11us exposed memory latency on the 7-deep serial row
// chain (VGPR=28 -> only 1-2 loads in flight). R12 (bulk 8-load prefetch
// ACROSS the barrier) regressed to ~41us: __syncthreads forces vmcnt(0)
// drain of all 8 loads with zero overlap, and 8 live float4 + addresses
// held across the barrier risks scratch spills at the (256,6) VGPR cap.
//
// R13: two INDEPENDENT row chains per wave + staged loads, no load crosses
// any barrier. The pair recurrence only couples adjacent rows, so rows
// 0-3 (chain A, 4 pair1 + 4 pair2) and rows 4-6 (chain B, 3 pair1 +
// 3 pair2, link 3->4 stays in A, 6->7 in B) split exactly. Chains are
// interleaved instruction-wise (2x ILP, serial depth 7 -> 4) and loads
// issue in 3 groups of <=2, >=2 steps ahead of use, pinned with
// sched_barrier(0) so the scheduler can't sink them to their uses.
// Peak live float4 = 5 (~45-50 VGPR, safe under the ~80 cap). Compiler
// emits counted vmcnt(N) per use -- never a full drain (T4/T14).
// Predicted: kernel 17.6 -> ~10-13us, dur_us 76.9 -> ~69-72.

#define H 224
#define W 224
#define STEPS 32
#define NBINS 33            // bin 32 (f==1.0 edge case) kept memory-safe, discarded
#define NCOL 64
#define BANDS 8
#define BAND_ROWS 28        // rows per block
#define SUB_ROWS 7          // rows per wave (4 waves per block)
#define NTHR 256

__device__ __forceinline__ int bin_of(float f) {
    // ceil(31*f) for f in [0,1): fma then trunc. 0.99999994f = 1-2^-24.
    return (int)fmaf(f, 31.0f, 0.99999994f);
}

struct BinState {
    int B0, B1, B2, B3, Bn, Bp;
};

__device__ __forceinline__ void init_state(BinState& S, float4 F,
                                           bool lastc, bool firstc)
{
    S.B0 = bin_of(F.x); S.B1 = bin_of(F.y);
    S.B2 = bin_of(F.z); S.B3 = bin_of(F.w);
    int t;
    t = __shfl_down(S.B0, 1); S.Bn = lastc  ? 64 : t;  // right: always-greater
    t = __shfl_up  (S.B3, 1); S.Bp = firstc ? 63 : t;  // left: never-smaller
}

// pair1: net vertex/h-edge updates at the 4 own pixels (unpredicated ds_add).
__device__ __forceinline__ void pair1_update(int* __restrict__ lhc,
                                             const BinState& S)
{
    int dm = (S.B0 > S.Bp) ? 1 : 0;
    int d0 = (S.B1 > S.B0) ? 1 : 0;
    int d1 = (S.B2 > S.B1) ? 1 : 0;
    int d2 = (S.B3 > S.B2) ? 1 : 0;
    int d3 = (S.Bn > S.B3) ? 1 : 0;
    atomicAdd(&lhc[S.B0 << 6], d0 - dm);
    atomicAdd(&lhc[S.B1 << 6], d1 - d0);
    atomicAdd(&lhc[S.B2 << 6], d2 - d1);
    atomicAdd(&lhc[S.B3 << 6], d3 - d2);
}

// pair2: net v-edge/square updates along M = max(B, C); rolls S <- C bins.
__device__ __forceinline__ void pair2_update_roll(int* __restrict__ lhc,
                                                  BinState& S, float4 G,
                                                  bool lastc, bool firstc)
{
    int C0 = bin_of(G.x), C1 = bin_of(G.y), C2 = bin_of(G.z), C3 = bin_of(G.w);
    int t;
    t = __shfl_down(C0, 1); int Cn = lastc  ? 64 : t;
    t = __shfl_up  (C3, 1); int Cp = firstc ? 63 : t;

    int M0 = max(S.B0, C0), M1 = max(S.B1, C1),
        M2 = max(S.B2, C2), M3 = max(S.B3, C3);
    int Mn = max(S.Bn, Cn), Mp = max(S.Bp, Cp);
    int em = (M0 > Mp) ? 1 : 0;
    int e0 = (M1 > M0) ? 1 : 0;
    int e1 = (M2 > M1) ? 1 : 0;
    int e2 = (M3 > M2) ? 1 : 0;
    int e3 = (Mn > M3) ? 1 : 0;
    atomicAdd(&lhc[M0 << 6], em - e0);
    atomicAdd(&lhc[M1 << 6], e0 - e1);
    atomicAdd(&lhc[M2 << 6], e1 - e2);
    atomicAdd(&lhc[M3 << 6], e2 - e3);

    S.B0 = C0; S.B1 = C1; S.B2 = C2; S.B3 = C3; S.Bn = Cn; S.Bp = Cp;
}

__global__ __launch_bounds__(NTHR, 6) void ecc_fused_kernel(
        const float* __restrict__ x, float* __restrict__ out)
{
    // Shared across the block's 4 waves. Update addr = (bin*64 + c)*4:
    // bank = c%32 -> 2-way wave aliasing (free, m136).
    __shared__ int lh[NBINS * NCOL];     // 8448 B
    __shared__ int bins[STEPS];

    const int tid  = threadIdx.x;

    // LDS init FIRST; the barrier fires with nothing in flight, so the
    // load pipeline below never hits a vmcnt(0) drain (R12 lesson).
    for (int i = tid; i < NBINS * NCOL; i += NTHR) lh[i] = 0;
    __syncthreads();

    const int band = blockIdx.x & (BANDS - 1);
    const int img  = blockIdx.x / BANDS;          // 0..191
    const float* __restrict__ p = x + (size_t)img * (H * W);

    const int c = tid & 63;      // column group: cols 4c..4c+3 (active c<56); c==lane
    const int s = tid >> 6;      // sub-band id == wave id (rows uniform per wave)
    const int r0 = band * BAND_ROWS + s * SUB_ROWS;

    if (c < 56) {
        const bool lastc    = (c == 55);
        const bool firstc   = (c == 0);
        const bool interior = (r0 != H - SUB_ROWS);
        int* __restrict__ lhc = lh + c;

        // Two address bases so rows fold into 13-bit load immediates:
        // A-rows (0..3) off baseA, B-rows (4..7) off baseB (offsets 0..2688B).
        const float* __restrict__ baseA = p + (size_t)r0 * W + (c << 2);
        const float* __restrict__ baseB = baseA + 4 * W;

        // --- Stage 1: 4 loads in flight (both chains' first two rows). ---
        float4 F0 = *(const float4*)(baseA);
        float4 F4 = *(const float4*)(baseB);
        float4 F1 = *(const float4*)(baseA + W);
        float4 F5 = *(const float4*)(baseB + W);
        __builtin_amdgcn_sched_barrier(0);   // loads stay issued here

        BinState SA, SB;
        init_state(SA, F0, lastc, firstc);
        init_state(SB, F4, lastc, firstc);
        pair1_update(lhc, SA);
        pair1_update(lhc, SB);

        // --- Stage 2 loads issue before F1/F5 are consumed. ---
        float4 F2 = *(const float4*)(baseA + 2 * W);
        float4 F6 = *(const float4*)(baseB + 2 * W);
        __builtin_amdgcn_sched_barrier(0);

        pair2_update_roll(lhc, SA, F1, lastc, firstc);
        pair2_update_roll(lhc, SB, F5, lastc, firstc);
        pair1_update(lhc, SA);
        pair1_update(lhc, SB);

        // --- Stage 3 loads (F7 clamped for the boundary wave: value unused). ---
        float4 F3 = *(const float4*)(baseA + 3 * W);
        float4 F7 = *(const float4*)(baseB + (interior ? 3 : 2) * W);
        __builtin_amdgcn_sched_barrier(0);

        pair2_update_roll(lhc, SA, F2, lastc, firstc);
        pair2_update_roll(lhc, SB, F6, lastc, firstc);
        pair1_update(lhc, SA);
        pair1_update(lhc, SB);

        pair2_update_roll(lhc, SA, F3, lastc, firstc);
        if (interior) {
            // interior chain B: 3rd pair2 links row r0+6 -> r0+7
            pair2_update_roll(lhc, SB, F7, lastc, firstc);
        }
        pair1_update(lhc, SA);                       // chain A row r0+3
        pair2_update_roll(lhc, SA, F4, lastc, firstc); // link r0+3 -> r0+4
    }
    __syncthreads();

    // Reduce 64 columns -> 32 bin sums (bin 32, if ever hit, discarded).
    // tid = b*8+g: 8-lane groups are 8-aligned, shfl_xor 1/2/4 stays in-group.
    const int b = tid >> 3;              // 0..31
    const int g = tid & 7;
    const int4* rowp = (const int4*)(lh + (b << 6) + (g << 3));
    int4 u0 = rowp[0], u1 = rowp[1];
    int sum = u0.x + u0.y + u0.z + u0.w + u1.x + u1.y + u1.z + u1.w;
    sum += __shfl_xor(sum, 1);
    sum += __shfl_xor(sum, 2);
    sum += __shfl_xor(sum, 4);
    if (g == 0) bins[b] = sum;
    __syncthreads();

    // Wave 0, lanes 0..31: inclusive prefix over bins, then one float
    // atomicAdd per bin into d_out (8 band blocks accumulate per image).
    if (tid < STEPS) {
        int v = bins[tid];
        #pragma unroll
        for (int off = 1; off < STEPS; off <<= 1) {
            int u = __shfl_up(v, off);
            if (tid >= off) v += u;
        }
        atomicAdd(&out[img * STEPS + tid], (float)v);
    }
}

extern "C" void kernel_launch(void* const* d_in, const int* in_sizes, int n_in,
                              void* d_out, int out_size, void* d_ws, size_t ws_size,
                              hipStream_t stream) {
    const float* x = (const float*)d_in[0];
    float* out = (float*)d_out;

    const int nimg = in_sizes[0] / (H * W);      // 192

    dim3 grid(nimg * BANDS);
    ecc_fused_kernel<<<grid, NTHR, 0, stream>>>(x, out);
}